// Round 1
// baseline (778.240 us; speedup 1.0000x reference)
//
#include <hip/hip_runtime.h>
#include <math.h>

namespace {

constexpr int B_  = 2;
constexpr int H_  = 96;
constexpr int W_  = 96;
constexpr int HW_ = H_ * W_;
constexpr int NC_ = 64;   // norm channels
constexpr int SC_ = 64;   // ref channels
constexpr int MID_ = 16;  // hidden channels of conv1

// ---------------------------------------------------------------------------
// positional_norm: per (b,h,w) mean/var over 64 channels (ddof=1)
// ---------------------------------------------------------------------------
__global__ __launch_bounds__(256)
void norm_kernel(const float* __restrict__ x, float* __restrict__ nrm) {
    int idx = blockIdx.x * 256 + threadIdx.x;           // over B*HW
    if (idx >= B_ * HW_) return;
    int b = idx / HW_, p = idx - b * HW_;
    const float* px = x + (size_t)b * NC_ * HW_ + p;
    float s1 = 0.f, s2 = 0.f;
    #pragma unroll
    for (int c = 0; c < NC_; ++c) {
        float v = px[c * HW_];
        s1 += v;
        s2 = fmaf(v, v, s2);
    }
    float mean = s1 * (1.f / NC_);
    float var  = (s2 - (float)NC_ * mean * mean) * (1.f / (NC_ - 1));
    float inv  = 1.f / sqrtf(var + 1e-5f);
    float* po = nrm + (size_t)b * NC_ * HW_ + p;
    #pragma unroll
    for (int c = 0; c < NC_; ++c)
        po[c * HW_] = (px[c * HW_] - mean) * inv;
}

// ---------------------------------------------------------------------------
// conv1: 3x3, Cin=128 (concat of normalized + ref), Cout=16, ReLU
// ---------------------------------------------------------------------------
__global__ __launch_bounds__(256)
void conv1_kernel(const float* __restrict__ nrm, const float* __restrict__ ref,
                  const float* __restrict__ wt, const float* __restrict__ bias,
                  float* __restrict__ out) {
    int idx = blockIdx.x * 256 + threadIdx.x;           // over B*MID*HW
    if (idx >= B_ * MID_ * HW_) return;
    int x  = idx % W_;
    int y  = (idx / W_) % H_;
    int oc = (idx / HW_) % MID_;
    int b  = idx / (HW_ * MID_);

    bool ok[9];
    #pragma unroll
    for (int t = 0; t < 9; ++t) {
        int yy = y + t / 3 - 1, xx = x + t % 3 - 1;
        ok[t] = ((unsigned)yy < (unsigned)H_) && ((unsigned)xx < (unsigned)W_);
    }

    float acc = bias[oc];
    const float* wp = wt + (size_t)oc * 128 * 9;
    size_t poff = (size_t)y * W_ + x;
    for (int ic = 0; ic < 128; ++ic) {
        const float* src = (ic < 64)
            ? (nrm + ((size_t)b * 64 + ic) * HW_)
            : (ref + ((size_t)b * 64 + (ic - 64)) * HW_);
        const float* base = src + poff;
        const float* wc = wp + ic * 9;
        #pragma unroll
        for (int t = 0; t < 9; ++t) {
            if (ok[t])
                acc = fmaf(wc[t], base[(t / 3 - 1) * W_ + (t % 3 - 1)], acc);
        }
    }
    out[idx] = fmaxf(acc, 0.f);
}

// ---------------------------------------------------------------------------
// generic direct 3x3 conv, pad 1
// ---------------------------------------------------------------------------
template <int CIN, int COUT, bool RELU>
__global__ __launch_bounds__(256)
void conv3x3_kernel(const float* __restrict__ in, const float* __restrict__ wt,
                    const float* __restrict__ bias, float* __restrict__ out) {
    int idx = blockIdx.x * 256 + threadIdx.x;           // over B*COUT*HW
    if (idx >= B_ * COUT * HW_) return;
    int x  = idx % W_;
    int y  = (idx / W_) % H_;
    int oc = (idx / HW_) % COUT;
    int b  = idx / (HW_ * COUT);

    bool ok[9];
    #pragma unroll
    for (int t = 0; t < 9; ++t) {
        int yy = y + t / 3 - 1, xx = x + t % 3 - 1;
        ok[t] = ((unsigned)yy < (unsigned)H_) && ((unsigned)xx < (unsigned)W_);
    }

    float acc = bias[oc];
    const float* wp = wt + (size_t)oc * CIN * 9;
    const float* ip = in + ((size_t)b * CIN) * HW_ + (size_t)y * W_ + x;
    for (int ic = 0; ic < CIN; ++ic) {
        const float* base = ip + (size_t)ic * HW_;
        const float* wc = wp + ic * 9;
        #pragma unroll
        for (int t = 0; t < 9; ++t) {
            if (ok[t])
                acc = fmaf(wc[t], base[(t / 3 - 1) * W_ + (t % 3 - 1)], acc);
        }
    }
    if (RELU) acc = fmaxf(acc, 0.f);
    out[idx] = acc;
}

// ---------------------------------------------------------------------------
// transpose w_dcn (O=64, C=64, 9) -> wkT[m=c*9+k][o]  (576 x 64)
// ---------------------------------------------------------------------------
__global__ __launch_bounds__(256)
void wt_transpose_kernel(const float* __restrict__ w_dcn, float* __restrict__ wkT) {
    int idx = blockIdx.x * 256 + threadIdx.x;           // over 576*64
    if (idx >= 576 * 64) return;
    int o = idx % 64;
    int m = idx / 64;                                   // m = c*9 + k
    int c = m / 9, k = m % 9;
    wkT[idx] = w_dcn[((size_t)o * 64 + c) * 9 + k];
}

// ---------------------------------------------------------------------------
// DCNv2 fused: per 16-pixel tile, stage mask-weighted bilinear samples in LDS
// (s[pos][c*9+k]), then matvec out[o] = sum_m wkT[m][o] * s[pos][m] + b_dcn[o]
// ---------------------------------------------------------------------------
constexpr int DTILE = 16;  // pixels per block; 9216/16 = 576 blocks per batch

__global__ __launch_bounds__(256)
void dcn_kernel(const float* __restrict__ ref, const float* __restrict__ om,
                const float* __restrict__ wkT, const float* __restrict__ b_dcn,
                float* __restrict__ out) {
    __shared__ float s[DTILE][576];                     // 36 KiB

    int b  = blockIdx.x / (HW_ / DTILE);
    int p0 = (blockIdx.x % (HW_ / DTILE)) * DTILE;
    int t  = threadIdx.x;

    const float* refb = ref + (size_t)b * SC_ * HW_;
    const float* omb  = om  + (size_t)b * 27  * HW_;

    // ---- phase 1: 16 pos x 9 taps = 144 (pos,k) pairs ----
    for (int pair = t; pair < DTILE * 9; pair += 256) {
        int pp = pair / 9;
        int k  = pair % 9;
        int p  = p0 + pp;
        int y  = p / W_, x = p % W_;

        float dy = omb[(2 * k)     * HW_ + p];
        float dx = omb[(2 * k + 1) * HW_ + p];
        float mk = omb[(18 + k)    * HW_ + p];
        mk = 1.f / (1.f + expf(-mk));                   // sigmoid

        float py = dy + (float)y + (float)(k / 3 - 1);
        float px = dx + (float)x + (float)(k % 3 - 1);
        float fy = floorf(py), fx = floorf(px);
        int   y0 = (int)fy,   x0 = (int)fx;
        float wy = py - fy,   wx = px - fx;

        float cw[4];
        int   cidx[4];
        #pragma unroll
        for (int i = 0; i < 4; ++i) {
            int yy = y0 + (i >> 1);
            int xx = x0 + (i & 1);
            bool valid = (yy >= 0) && (yy < H_) && (xx >= 0) && (xx < W_);
            int yc = yy < 0 ? 0 : (yy > H_ - 1 ? H_ - 1 : yy);
            int xc = xx < 0 ? 0 : (xx > W_ - 1 ? W_ - 1 : xx);
            cidx[i] = yc * W_ + xc;
            float wyi = (i >> 1) ? wy : (1.f - wy);
            float wxi = (i & 1)  ? wx : (1.f - wx);
            cw[i] = valid ? wyi * wxi : 0.f;
        }

        for (int c = 0; c < SC_; ++c) {
            const float* rc = refb + (size_t)c * HW_;
            float v = cw[0] * rc[cidx[0]] + cw[1] * rc[cidx[1]]
                    + cw[2] * rc[cidx[2]] + cw[3] * rc[cidx[3]];
            s[pp][c * 9 + k] = mk * v;
        }
    }
    __syncthreads();

    // ---- phase 2: out[o][pos] = sum_m wkT[m][o] * s[pos][m] ----
    int o   = t & 63;
    int grp = t >> 6;                                   // 0..3
    constexpr int PP = DTILE / 4;                       // 4 positions per group

    float acc[PP];
    float bo = b_dcn[o];
    #pragma unroll
    for (int i = 0; i < PP; ++i) acc[i] = bo;

    for (int m4 = 0; m4 < 576; m4 += 4) {
        float w0 = wkT[(m4 + 0) * 64 + o];
        float w1 = wkT[(m4 + 1) * 64 + o];
        float w2 = wkT[(m4 + 2) * 64 + o];
        float w3 = wkT[(m4 + 3) * 64 + o];
        #pragma unroll
        for (int i = 0; i < PP; ++i) {
            const float4 sv = *reinterpret_cast<const float4*>(&s[grp * PP + i][m4]);
            acc[i] = fmaf(w0, sv.x, acc[i]);
            acc[i] = fmaf(w1, sv.y, acc[i]);
            acc[i] = fmaf(w2, sv.z, acc[i]);
            acc[i] = fmaf(w3, sv.w, acc[i]);
        }
    }

    float* outb = out + (size_t)b * SC_ * HW_;
    #pragma unroll
    for (int i = 0; i < PP; ++i) {
        int p = p0 + grp * PP + i;
        outb[(size_t)o * HW_ + p] = acc[i];
    }
}

// ---------------------------------------------------------------------------
// final: gamma = conv(rr, w_g), beta = conv(rr, w_be);
//        out = normalized * (1 + gamma) + beta
// ---------------------------------------------------------------------------
__global__ __launch_bounds__(256)
void final_kernel(const float* __restrict__ rr, const float* __restrict__ nrm,
                  const float* __restrict__ w_g, const float* __restrict__ b_g,
                  const float* __restrict__ w_be, const float* __restrict__ b_be,
                  float* __restrict__ out) {
    int idx = blockIdx.x * 256 + threadIdx.x;           // over B*NC*HW
    if (idx >= B_ * NC_ * HW_) return;
    int x  = idx % W_;
    int y  = (idx / W_) % H_;
    int oc = (idx / HW_) % NC_;
    int b  = idx / (HW_ * NC_);

    bool ok[9];
    #pragma unroll
    for (int t = 0; t < 9; ++t) {
        int yy = y + t / 3 - 1, xx = x + t % 3 - 1;
        ok[t] = ((unsigned)yy < (unsigned)H_) && ((unsigned)xx < (unsigned)W_);
    }

    float ag = b_g[oc];
    float ab = b_be[oc];
    const float* wgp = w_g  + (size_t)oc * SC_ * 9;
    const float* wbp = w_be + (size_t)oc * SC_ * 9;
    const float* ip  = rr + ((size_t)b * SC_) * HW_ + (size_t)y * W_ + x;
    for (int ic = 0; ic < SC_; ++ic) {
        const float* base = ip + (size_t)ic * HW_;
        const float* wgc = wgp + ic * 9;
        const float* wbc = wbp + ic * 9;
        #pragma unroll
        for (int t = 0; t < 9; ++t) {
            if (ok[t]) {
                float v = base[(t / 3 - 1) * W_ + (t % 3 - 1)];
                ag = fmaf(wgc[t], v, ag);
                ab = fmaf(wbc[t], v, ab);
            }
        }
    }
    float n = nrm[idx];
    out[idx] = fmaf(n, 1.f + ag, ab + n * 0.f);
}

} // namespace

// ---------------------------------------------------------------------------
extern "C" void kernel_launch(void* const* d_in, const int* in_sizes, int n_in,
                              void* d_out, int out_size, void* d_ws, size_t ws_size,
                              hipStream_t stream) {
    (void)in_sizes; (void)n_in; (void)out_size; (void)ws_size;

    const float* x     = (const float*)d_in[0];
    const float* ref   = (const float*)d_in[1];
    const float* w1    = (const float*)d_in[2];
    const float* b1    = (const float*)d_in[3];
    const float* w2    = (const float*)d_in[4];
    const float* b2    = (const float*)d_in[5];
    const float* w_off = (const float*)d_in[6];
    const float* b_off = (const float*)d_in[7];
    const float* w_dcn = (const float*)d_in[8];
    const float* b_dcn = (const float*)d_in[9];
    const float* w_g   = (const float*)d_in[10];
    const float* b_g   = (const float*)d_in[11];
    const float* w_be  = (const float*)d_in[12];
    const float* b_be  = (const float*)d_in[13];

    float* out = (float*)d_out;
    float* ws  = (float*)d_ws;

    // workspace layout (floats)
    float* nrm  = ws;                       // B*64*HW   = 1,179,648
    float* hmid = nrm  + 1179648;           // B*16*HW   =   294,912
    float* cond = hmid + 294912;            // B*64*HW   = 1,179,648
    float* om   = cond + 1179648;           // B*27*HW   =   497,664
    float* wkT  = om   + 497664;            // 576*64    =    36,864
    float* rr   = wkT  + 36864;             // B*64*HW   = 1,179,648
                                            // total ~17.5 MB

    norm_kernel<<<(B_ * HW_ + 255) / 256, 256, 0, stream>>>(x, nrm);

    conv1_kernel<<<(B_ * MID_ * HW_ + 255) / 256, 256, 0, stream>>>(
        nrm, ref, w1, b1, hmid);

    conv3x3_kernel<16, 64, true><<<(B_ * 64 * HW_ + 255) / 256, 256, 0, stream>>>(
        hmid, w2, b2, cond);

    conv3x3_kernel<64, 27, false><<<(B_ * 27 * HW_ + 255) / 256, 256, 0, stream>>>(
        cond, w_off, b_off, om);

    wt_transpose_kernel<<<(576 * 64 + 255) / 256, 256, 0, stream>>>(w_dcn, wkT);

    dcn_kernel<<<B_ * (HW_ / DTILE), 256, 0, stream>>>(ref, om, wkT, b_dcn, rr);

    final_kernel<<<(B_ * NC_ * HW_ + 255) / 256, 256, 0, stream>>>(
        rr, nrm, w_g, b_g, w_be, b_be, out);
}

// Round 2
// 294.149 us; speedup vs baseline: 2.6457x; 2.6457x over previous
//
#include <hip/hip_runtime.h>
#include <math.h>

namespace {

constexpr int B_  = 2;
constexpr int H_  = 96;
constexpr int W_  = 96;
constexpr int HW_ = H_ * W_;
constexpr int NC_ = 64;
constexpr int SC_ = 64;

// ---------------------------------------------------------------------------
// prep: transpose all conv weights to wT[ic][tap][oc] (oc contiguous);
// pad w_off's COUT 27->32; build dcn wkT[m=c*9+k][o].
// ---------------------------------------------------------------------------
__global__ __launch_bounds__(256)
void prep_weights(const float* __restrict__ w1, const float* __restrict__ w2,
                  const float* __restrict__ woff, const float* __restrict__ wg,
                  const float* __restrict__ wbe, const float* __restrict__ wdcn,
                  float* __restrict__ w1T, float* __restrict__ w2T,
                  float* __restrict__ woffT, float* __restrict__ wgT,
                  float* __restrict__ wbeT, float* __restrict__ wkT) {
    int idx = blockIdx.x * 256 + threadIdx.x;
    if (idx < 128 * 9 * 16) {   // w1: O=16, I=128
        int oc = idx % 16, rem = idx / 16, tap = rem % 9, ic = rem / 9;
        w1T[idx] = w1[(oc * 128 + ic) * 9 + tap];
    }
    if (idx < 16 * 9 * 64) {    // w2: O=64, I=16
        int oc = idx % 64, rem = idx / 64, tap = rem % 9, ic = rem / 9;
        w2T[idx] = w2[(oc * 16 + ic) * 9 + tap];
    }
    if (idx < 64 * 9 * 32) {    // w_off: O=27 (pad 32), I=64
        int oc = idx % 32, rem = idx / 32, tap = rem % 9, ic = rem / 9;
        woffT[idx] = (oc < 27) ? woff[(oc * 64 + ic) * 9 + tap] : 0.f;
    }
    if (idx < 64 * 9 * 64) {    // w_g / w_be / w_dcn: O=64, I=64
        int oc = idx % 64, rem = idx / 64, tap = rem % 9, ic = rem / 9;
        wgT[idx]  = wg  [(oc * 64 + ic) * 9 + tap];
        wbeT[idx] = wbe [(oc * 64 + ic) * 9 + tap];
        wkT[idx]  = wdcn[(oc * 64 + ic) * 9 + tap];  // wkT[m=ic*9+tap][oc]
    }
}

// ---------------------------------------------------------------------------
// positional_norm
// ---------------------------------------------------------------------------
__global__ __launch_bounds__(256)
void norm_kernel(const float* __restrict__ x, float* __restrict__ nrm) {
    int idx = blockIdx.x * 256 + threadIdx.x;
    if (idx >= B_ * HW_) return;
    int b = idx / HW_, p = idx - b * HW_;
    const float* px = x + (size_t)b * NC_ * HW_ + p;
    float s1 = 0.f, s2 = 0.f;
    #pragma unroll
    for (int c = 0; c < NC_; ++c) {
        float v = px[c * HW_];
        s1 += v;
        s2 = fmaf(v, v, s2);
    }
    float mean = s1 * (1.f / NC_);
    float var  = (s2 - (float)NC_ * mean * mean) * (1.f / (NC_ - 1));
    float inv  = 1.f / sqrtf(var + 1e-5f);
    float* po = nrm + (size_t)b * NC_ * HW_ + p;
    #pragma unroll
    for (int c = 0; c < NC_; ++c)
        po[c * HW_] = (px[c * HW_] - mean) * inv;
}

// ---------------------------------------------------------------------------
// tiled implicit-GEMM 3x3 conv, pad 1.
// Block: 64-pixel tile (16 wide x 4 high) x COUT channels.
// LDS: patch[ICB][6][18] + weights wT-chunk [ICB][9][COUT] (x2 if DUAL).
// Thread: NOC oc x 4 px register tile. THREADS = (COUT/NOC)*16.
// DUAL: second weight/bias set (beta) + fused epilogue out = nrm*(1+g)+b.
// ---------------------------------------------------------------------------
template <int CIN1, int CIN2, int COUT, int COUT_REAL, int NOC, int ICB,
          bool RELU, bool DUAL, int THREADS>
__global__ __launch_bounds__(THREADS)
void conv_tiled(const float* __restrict__ in1, const float* __restrict__ in2,
                const float* __restrict__ wT, const float* __restrict__ wT2,
                const float* __restrict__ bias, const float* __restrict__ bias2,
                const float* __restrict__ nrm, float* __restrict__ out) {
    constexpr int CIN = CIN1 + CIN2;
    static_assert(THREADS == (COUT / NOC) * 16, "thread count mismatch");
    constexpr int WSTRIDE = ICB * 9 * COUT;

    __shared__ float patch[ICB][6][18];
    __shared__ float wlds[(DUAL ? 2 : 1) * WSTRIDE];

    int t   = threadIdx.x;
    int blk = blockIdx.x;                 // 288 = B * (H/4) * (W/16)
    int bx  = blk % 6;
    int by  = (blk / 6) % 24;
    int b   = blk / (6 * 24);
    int x0  = bx * 16, y0 = by * 4;

    int pxg = t & 15, ocg = t >> 4;
    int py  = pxg >> 2, px0 = (pxg & 3) * 4;
    int oc0 = ocg * NOC;

    float accA[NOC][4];
    float accB[NOC][4];
    #pragma unroll
    for (int n = 0; n < NOC; ++n) {
        float bA = (oc0 + n < COUT_REAL) ? bias[oc0 + n] : 0.f;
        float bB = DUAL ? ((oc0 + n < COUT_REAL) ? bias2[oc0 + n] : 0.f) : 0.f;
        #pragma unroll
        for (int i = 0; i < 4; ++i) { accA[n][i] = bA; accB[n][i] = bB; }
    }

    for (int ic0 = 0; ic0 < CIN; ic0 += ICB) {
        // ---- stage input patch chunk ----
        for (int e = t; e < ICB * 108; e += THREADS) {
            int col = e % 18;
            int row = (e / 18) % 6;
            int ic  = e / 108;
            int yy = y0 + row - 1, xx = x0 + col - 1;
            float v = 0.f;
            if ((unsigned)yy < (unsigned)H_ && (unsigned)xx < (unsigned)W_) {
                int c = ic0 + ic;
                const float* src = (c < CIN1)
                    ? in1 + ((size_t)b * CIN1 + c) * HW_
                    : in2 + ((size_t)b * CIN2 + (c - CIN1)) * HW_;
                v = src[yy * W_ + xx];
            }
            patch[ic][row][col] = v;
        }
        // ---- stage weight chunk(s), float4 copies ----
        {
            constexpr int W4 = WSTRIDE / 4;
            const float4* wsrc = (const float4*)(wT + (size_t)ic0 * 9 * COUT);
            float4* wdst = (float4*)&wlds[0];
            for (int j = t; j < W4; j += THREADS) wdst[j] = wsrc[j];
            if (DUAL) {
                const float4* ws2 = (const float4*)(wT2 + (size_t)ic0 * 9 * COUT);
                float4* wd2 = (float4*)&wlds[WSTRIDE];
                for (int j = t; j < W4; j += THREADS) wd2[j] = ws2[j];
            }
        }
        __syncthreads();

        // ---- accumulate ----
        for (int icc = 0; icc < ICB; ++icc) {
            float r[3][6];
            #pragma unroll
            for (int dy = 0; dy < 3; ++dy)
                #pragma unroll
                for (int j = 0; j < 6; ++j)
                    r[dy][j] = patch[icc][py + dy][px0 + j];

            #pragma unroll
            for (int tap = 0; tap < 9; ++tap) {
                int dy = tap / 3, dx = tap % 3;
                const float* wrow = &wlds[(icc * 9 + tap) * COUT + oc0];
                #pragma unroll
                for (int n = 0; n < NOC; ++n) {
                    float wv = wrow[n];
                    #pragma unroll
                    for (int i = 0; i < 4; ++i)
                        accA[n][i] = fmaf(wv, r[dy][dx + i], accA[n][i]);
                }
                if (DUAL) {
                    const float* wrow2 = &wlds[WSTRIDE + (icc * 9 + tap) * COUT + oc0];
                    #pragma unroll
                    for (int n = 0; n < NOC; ++n) {
                        float wv = wrow2[n];
                        #pragma unroll
                        for (int i = 0; i < 4; ++i)
                            accB[n][i] = fmaf(wv, r[dy][dx + i], accB[n][i]);
                    }
                }
            }
        }
        __syncthreads();
    }

    // ---- epilogue ----
    int xg = x0 + px0, yg = y0 + py;
    #pragma unroll
    for (int n = 0; n < NOC; ++n) {
        int oc = oc0 + n;
        if (oc >= COUT_REAL) continue;
        size_t off = ((size_t)b * COUT_REAL + oc) * HW_ + (size_t)yg * W_ + xg;
        float4 o4;
        if (DUAL) {
            const float4 nv = *reinterpret_cast<const float4*>(&nrm[off]);
            o4.x = fmaf(nv.x, 1.f + accA[n][0], accB[n][0]);
            o4.y = fmaf(nv.y, 1.f + accA[n][1], accB[n][1]);
            o4.z = fmaf(nv.z, 1.f + accA[n][2], accB[n][2]);
            o4.w = fmaf(nv.w, 1.f + accA[n][3], accB[n][3]);
        } else {
            o4.x = RELU ? fmaxf(accA[n][0], 0.f) : accA[n][0];
            o4.y = RELU ? fmaxf(accA[n][1], 0.f) : accA[n][1];
            o4.z = RELU ? fmaxf(accA[n][2], 0.f) : accA[n][2];
            o4.w = RELU ? fmaxf(accA[n][3], 0.f) : accA[n][3];
        }
        *reinterpret_cast<float4*>(&out[off]) = o4;
    }
}

// ---------------------------------------------------------------------------
// DCNv2 fused (unchanged from round 1; wkT now from prep kernel)
// ---------------------------------------------------------------------------
constexpr int DTILE = 16;

__global__ __launch_bounds__(256)
void dcn_kernel(const float* __restrict__ ref, const float* __restrict__ om,
                const float* __restrict__ wkT, const float* __restrict__ b_dcn,
                float* __restrict__ out) {
    __shared__ float s[DTILE][576];

    int b  = blockIdx.x / (HW_ / DTILE);
    int p0 = (blockIdx.x % (HW_ / DTILE)) * DTILE;
    int t  = threadIdx.x;

    const float* refb = ref + (size_t)b * SC_ * HW_;
    const float* omb  = om  + (size_t)b * 27  * HW_;

    for (int pair = t; pair < DTILE * 9; pair += 256) {
        int pp = pair / 9;
        int k  = pair % 9;
        int p  = p0 + pp;
        int y  = p / W_, x = p % W_;

        float dy = omb[(2 * k)     * HW_ + p];
        float dx = omb[(2 * k + 1) * HW_ + p];
        float mk = omb[(18 + k)    * HW_ + p];
        mk = 1.f / (1.f + expf(-mk));

        float py = dy + (float)y + (float)(k / 3 - 1);
        float px = dx + (float)x + (float)(k % 3 - 1);
        float fy = floorf(py), fx = floorf(px);
        int   y0 = (int)fy,   x0 = (int)fx;
        float wy = py - fy,   wx = px - fx;

        float cw[4];
        int   cidx[4];
        #pragma unroll
        for (int i = 0; i < 4; ++i) {
            int yy = y0 + (i >> 1);
            int xx = x0 + (i & 1);
            bool valid = (yy >= 0) && (yy < H_) && (xx >= 0) && (xx < W_);
            int yc = yy < 0 ? 0 : (yy > H_ - 1 ? H_ - 1 : yy);
            int xc = xx < 0 ? 0 : (xx > W_ - 1 ? W_ - 1 : xx);
            cidx[i] = yc * W_ + xc;
            float wyi = (i >> 1) ? wy : (1.f - wy);
            float wxi = (i & 1)  ? wx : (1.f - wx);
            cw[i] = valid ? wyi * wxi : 0.f;
        }

        for (int c = 0; c < SC_; ++c) {
            const float* rc = refb + (size_t)c * HW_;
            float v = cw[0] * rc[cidx[0]] + cw[1] * rc[cidx[1]]
                    + cw[2] * rc[cidx[2]] + cw[3] * rc[cidx[3]];
            s[pp][c * 9 + k] = mk * v;
        }
    }
    __syncthreads();

    int o   = t & 63;
    int grp = t >> 6;
    constexpr int PP = DTILE / 4;

    float acc[PP];
    float bo = b_dcn[o];
    #pragma unroll
    for (int i = 0; i < PP; ++i) acc[i] = bo;

    for (int m4 = 0; m4 < 576; m4 += 4) {
        float w0 = wkT[(m4 + 0) * 64 + o];
        float w1 = wkT[(m4 + 1) * 64 + o];
        float w2 = wkT[(m4 + 2) * 64 + o];
        float w3 = wkT[(m4 + 3) * 64 + o];
        #pragma unroll
        for (int i = 0; i < PP; ++i) {
            const float4 sv = *reinterpret_cast<const float4*>(&s[grp * PP + i][m4]);
            acc[i] = fmaf(w0, sv.x, acc[i]);
            acc[i] = fmaf(w1, sv.y, acc[i]);
            acc[i] = fmaf(w2, sv.z, acc[i]);
            acc[i] = fmaf(w3, sv.w, acc[i]);
        }
    }

    float* outb = out + (size_t)b * SC_ * HW_;
    #pragma unroll
    for (int i = 0; i < PP; ++i) {
        int p = p0 + grp * PP + i;
        outb[(size_t)o * HW_ + p] = acc[i];
    }
}

} // namespace

// ---------------------------------------------------------------------------
extern "C" void kernel_launch(void* const* d_in, const int* in_sizes, int n_in,
                              void* d_out, int out_size, void* d_ws, size_t ws_size,
                              hipStream_t stream) {
    (void)in_sizes; (void)n_in; (void)out_size; (void)ws_size;

    const float* x     = (const float*)d_in[0];
    const float* ref   = (const float*)d_in[1];
    const float* w1    = (const float*)d_in[2];
    const float* b1    = (const float*)d_in[3];
    const float* w2    = (const float*)d_in[4];
    const float* b2    = (const float*)d_in[5];
    const float* w_off = (const float*)d_in[6];
    const float* b_off = (const float*)d_in[7];
    const float* w_dcn = (const float*)d_in[8];
    const float* b_dcn = (const float*)d_in[9];
    const float* w_g   = (const float*)d_in[10];
    const float* b_g   = (const float*)d_in[11];
    const float* w_be  = (const float*)d_in[12];
    const float* b_be  = (const float*)d_in[13];

    float* out = (float*)d_out;
    float* ws  = (float*)d_ws;

    // workspace layout (floats)
    float* nrm   = ws;                      // 1,179,648
    float* hmid  = nrm   + 1179648;         //   294,912
    float* cond  = hmid  + 294912;          // 1,179,648
    float* om    = cond  + 1179648;         //   497,664
    float* rr    = om    + 497664;          // 1,179,648
    float* w1T   = rr    + 1179648;         //    18,432
    float* w2T   = w1T   + 18432;           //     9,216
    float* woffT = w2T   + 9216;            //    18,432
    float* wgT   = woffT + 18432;           //    36,864
    float* wbeT  = wgT   + 36864;           //    36,864
    float* wkT   = wbeT  + 36864;           //    36,864  (total ~18 MB)

    prep_weights<<<144, 256, 0, stream>>>(w1, w2, w_off, w_g, w_be, w_dcn,
                                          w1T, w2T, woffT, wgT, wbeT, wkT);

    norm_kernel<<<(B_ * HW_ + 255) / 256, 256, 0, stream>>>(x, nrm);

    constexpr int GRID = B_ * (H_ / 4) * (W_ / 16);   // 288

    // conv1: 128 -> 16, ReLU. NOC=2 -> 128 threads.
    conv_tiled<64, 64, 16, 16, 2, 16, true, false, 128>
        <<<GRID, 128, 0, stream>>>(nrm, ref, w1T, nullptr, b1, nullptr, nullptr, hmid);

    // conv2: 16 -> 64, ReLU. NOC=4 -> 256 threads.
    conv_tiled<16, 0, 64, 64, 4, 16, true, false, 256>
        <<<GRID, 256, 0, stream>>>(hmid, nullptr, w2T, nullptr, b2, nullptr, nullptr, cond);

    // conv_off: 64 -> 27 (padded 32). NOC=2 -> 256 threads.
    conv_tiled<64, 0, 32, 27, 2, 16, false, false, 256>
        <<<GRID, 256, 0, stream>>>(cond, nullptr, woffT, nullptr, b_off, nullptr, nullptr, om);

    dcn_kernel<<<B_ * (HW_ / DTILE), 256, 0, stream>>>(ref, om, wkT, b_dcn, rr);

    // final: gamma/beta convs 64->64 DUAL + fused affine epilogue. ICB=8.
    conv_tiled<64, 0, 64, 64, 4, 8, false, true, 256>
        <<<GRID, 256, 0, stream>>>(rr, nullptr, wgT, wbeT, b_g, b_be, nrm, out);
}